// Round 6
// baseline (6900.145 us; speedup 1.0000x reference)
//
#include <hip/hip_runtime.h>

// Problem constants (from reference)
#define NB    32
#define KJ    17
#define CIN   2048
#define HWSZ  4096     // H*W = 64*64
#define WDIM  64
#define CEMB  2112     // 64 + 2048
#define HID   128
#define NROWS (NB*KJ)  // 544
#define SPLITK 4

// Diagnostic replication (round 6): resolve feat & gcn per-iter costs.
// T6 = T5 + 255*feat + 63*gcn; the larger product shows in top-5 with counters.
#define REP_FEAT 256
#define REP_GCN  64

// Skeleton adjacency mask (H36M edges + diagonal), row i -> bitmask over j
__device__ __constant__ unsigned c_mask[KJ] = {
  0x00093u, 0x00007u, 0x0000Eu, 0x0000Cu, 0x00031u, 0x00070u, 0x00060u,
  0x00181u, 0x04B80u, 0x00700u, 0x00600u, 0x01900u, 0x03800u, 0x03000u,
  0x0C100u, 0x1C000u, 0x18000u
};

// ---------------------------------------------------------------------------
// K_pack: repack Wi and Wh into c4-interleaved layout for float4 weight loads.
// ---------------------------------------------------------------------------
__global__ __launch_bounds__(256) void k_pack(
    const float* __restrict__ Wi, const float* __restrict__ Wh,
    float* __restrict__ Wpi, float* __restrict__ Wph) {
  const int idx = blockIdx.x * 256 + threadIdx.x;   // 2112*256 = 540672 threads
  {
    const int d = idx & 127;
    const int rest = idx >> 7;          // p*2112 + c
    const int c = rest % CEMB, p = rest / CEMB;
    Wpi[(((size_t)p * 528 + (c >> 2)) * 128 + d) * 4 + (c & 3)] = Wi[idx];
  }
  if (idx < 8 * 2 * HID * HID) {        // 262144
    const int d = idx & 127;
    const int rest = idx >> 7;          // lp*128 + c
    const int c = rest & 127, lp = rest >> 7;
    Wph[(((size_t)lp * 32 + (c >> 2)) * 128 + d) * 4 + (c & 3)] = Wh[idx];
  }
}

// ---------------------------------------------------------------------------
// K_loc: per-(n,k) heatmap argmax -> locs[544]; also posemb MLP -> h[:,0:64]
// ---------------------------------------------------------------------------
__global__ __launch_bounds__(256) void k_loc(
    const float* __restrict__ heatmap, const float* __restrict__ bbox,
    const float* __restrict__ pos_w, const float* __restrict__ pos_b,
    float* __restrict__ h_ws, int* __restrict__ locs) {
  const int b = blockIdx.x;          // n*17 + k
  const int n = b / KJ;
  const int t = threadIdx.x;

  __shared__ float svals[256];
  __shared__ int   sidx[256];

  const float4* hm4 = (const float4*)(heatmap + (size_t)b * HWSZ);
  float best = -1e30f; int bidx = 0;
  #pragma unroll
  for (int k = 0; k < 4; ++k) {
    const int vi = k * 256 + t;
    const float4 v = hm4[vi];
    const int base = vi * 4;
    if (v.x > best) { best = v.x; bidx = base;     }
    if (v.y > best) { best = v.y; bidx = base + 1; }
    if (v.z > best) { best = v.z; bidx = base + 2; }
    if (v.w > best) { best = v.w; bidx = base + 3; }
  }
  svals[t] = best; sidx[t] = bidx;
  __syncthreads();
  for (int s = 128; s > 0; s >>= 1) {
    if (t < s) {
      const float v2 = svals[t + s]; const int i2 = sidx[t + s];
      if (v2 > svals[t] || (v2 == svals[t] && i2 < sidx[t])) {
        svals[t] = v2; sidx[t] = i2;
      }
    }
    __syncthreads();
  }
  const int loc = sidx[0];
  if (t == 0) locs[b] = loc;

  if (t < 64) {
    const float kx = (float)(loc & (WDIM - 1));
    const float ky = (float)(loc >> 6);
    float in6[6];
    in6[0] = kx * (2.0f / 64.0f) - 1.0f;
    in6[1] = ky * (2.0f / 64.0f) - 1.0f;
    in6[2] = bbox[n * 4 + 0] * (2.0f / 1920.0f) - 1.0f;
    in6[3] = bbox[n * 4 + 1] * (2.0f / 1080.0f) - 1.0f;
    in6[4] = bbox[n * 4 + 2] * (1.0f / 1920.0f);
    in6[5] = bbox[n * 4 + 3] * (1.0f / 1080.0f);
    float acc = pos_b[t];
    #pragma unroll
    for (int c = 0; c < 6; ++c) acc = fmaf(in6[c], pos_w[c * 64 + t], acc);
    h_ws[(size_t)b * CEMB + t] = acc;
  }
}

// ---------------------------------------------------------------------------
// K_feat: scattered feature gather x[n, c, loc] -> h[:,64:2112]
// grid (544, 4). REP rotation is bijective over channels; stores idempotent.
// ---------------------------------------------------------------------------
__global__ __launch_bounds__(256) void k_feat(
    const float* __restrict__ x, const int* __restrict__ locs,
    float* __restrict__ h_ws, int rep) {
  const int b = blockIdx.x;
  const int n = b / KJ;
  const int t = threadIdx.x;
  const int loc = locs[b];
  const int c0 = blockIdx.y * 512 + t;
  const float* xn = x + (size_t)n * CIN * HWSZ + loc;
  float* hrow = h_ws + (size_t)b * CEMB + 64;
  for (int it = 0; it < rep; ++it) {
    const int cA = (c0 + it * 64) & 2047;
    const int cB = (c0 + 256 + it * 64) & 2047;
    const float v0 = xn[(size_t)cA * HWSZ];
    const float v1 = xn[(size_t)cB * HWSZ];
    hrow[cA] = v0;
    hrow[cB] = v1;
  }
}

// ---------------------------------------------------------------------------
// K_gemm: input GEMM  C[544][256] = h[544][2112] @ [Wi0|Wi1], split-K=4
// grid (34, 4, 4), block 256. Packed-W float4 loads + depth-2 prefetch ring.
// ---------------------------------------------------------------------------
__global__ __launch_bounds__(256) void k_gemm_in(
    const float* __restrict__ h_ws, const float* __restrict__ Wpi,
    float* __restrict__ part) {
  const int bm = blockIdx.x, bn = blockIdx.y, bz = blockIdx.z;
  const int t = threadIdx.x;
  const int lane = t & 63, g = t >> 6;          // row group (4 rows each)
  const int j = bn * 64 + lane;                 // output col 0..255
  const int p = j >> 7, d = j & 127;
  const int row0 = bm * 16;

  const float4* W4 = (const float4*)Wpi + ((size_t)p * 528 + bz * 132) * 128 + d;
  const int k0 = bz * 528;

  __shared__ float At[16][48];                  // 12 c4-chunks per stage
  float acc[4] = {0.f, 0.f, 0.f, 0.f};

  float4 wc = W4[0];
  float4 wn = W4[128];
  int cc = 0;                                    // chunk index 0..131
  for (int st = 0; st < 11; ++st) {
    const int kk = k0 + st * 48;
    __syncthreads();
    for (int idx = t; idx < 16 * 48; idx += 256) {
      const int r = idx / 48, c = idx - r * 48;
      At[r][c] = h_ws[(size_t)(row0 + r) * CEMB + kk + c];
    }
    __syncthreads();
    #pragma unroll
    for (int u = 0; u < 12; ++u, ++cc) {
      const int nf = (cc + 2 < 132) ? cc + 2 : 131;
      const float4 wf = W4[(size_t)nf * 128];
      #pragma unroll
      for (int r = 0; r < 4; ++r) {
        const float4 s = *(const float4*)&At[g * 4 + r][u * 4];
        acc[r] = fmaf(s.x, wc.x, fmaf(s.y, wc.y, fmaf(s.z, wc.z, fmaf(s.w, wc.w, acc[r]))));
      }
      wc = wn; wn = wf;
    }
  }
  #pragma unroll
  for (int r = 0; r < 4; ++r) {
    part[((size_t)bz * NROWS + row0 + g * 4 + r) * 256 + j] = acc[r];
  }
}

// ---------------------------------------------------------------------------
// K_gcn: adjacency softmax + input mix + 4 residual blocks + output gconv.
// grid 32, block 512. Packed-W float4 + depth-3 prefetch ring. REP loop for
// diagnostics (idempotent; trailing barrier protects shared reuse).
// ---------------------------------------------------------------------------
__device__ __forceinline__ void layer2(
    const float (*S)[HID], const float4* __restrict__ W0,
    const float4* __restrict__ W1, float (*O0)[HID], float (*O1)[HID],
    int q, int j) {
  const int r0 = q * 5;                 // rows r0..r0+4 (rows 17..19 are pad)
  float a0[5] = {0.f, 0.f, 0.f, 0.f, 0.f};
  float a1[5] = {0.f, 0.f, 0.f, 0.f, 0.f};

  float4 w0A = W0[j],           w1A = W1[j];
  float4 w0B = W0[128 + j],     w1B = W1[128 + j];
  float4 w0C = W0[256 + j],     w1C = W1[256 + j];
  for (int cc = 0; cc < 32; ++cc) {
    const int nf = (cc + 3 < 32) ? cc + 3 : 31;
    const float4 w0F = W0[nf * 128 + j];
    const float4 w1F = W1[nf * 128 + j];
    #pragma unroll
    for (int r = 0; r < 5; ++r) {
      const float4 s = *(const float4*)&S[r0 + r][cc * 4];  // wave-uniform bcast
      a0[r] = fmaf(s.x, w0A.x, fmaf(s.y, w0A.y, fmaf(s.z, w0A.z, fmaf(s.w, w0A.w, a0[r]))));
      a1[r] = fmaf(s.x, w1A.x, fmaf(s.y, w1A.y, fmaf(s.z, w1A.z, fmaf(s.w, w1A.w, a1[r]))));
    }
    w0A = w0B; w0B = w0C; w0C = w0F;
    w1A = w1B; w1B = w1C; w1C = w1F;
  }
  #pragma unroll
  for (int r = 0; r < 5; ++r) { O0[r0 + r][j] = a0[r]; O1[r0 + r][j] = a1[r]; }
}

template <int ADD>
__device__ __forceinline__ void mix_bn2(
    const float (*T0)[HID], const float (*T1)[HID], const float (*A)[KJ],
    float pb, float pg, float pt, float (*dst)[HID], int q, int d) {
  const float gsv = pg * 0.99999500003749969f;  // gamma * rsqrt(1+1e-5)
  for (int i = q; i < KJ; i += 4) {
    float s = 0.f;
    #pragma unroll
    for (int jj = 0; jj < KJ; ++jj) s = fmaf(A[i][jj], T1[jj][d], s);
    s += A[i][i] * (T0[i][d] - T1[i][d]);   // diag term h1 -> h0
    const float v = fmaxf(fmaf(s + pb, gsv, pt), 0.f);
    if (ADD) dst[i][d] += v; else dst[i][d] = v;
  }
}

__global__ __launch_bounds__(512) void k_gcn(
    const float* __restrict__ part,
    const float* __restrict__ Ei, const float* __restrict__ bi,
    const float* __restrict__ gi, const float* __restrict__ bti,
    const float* __restrict__ Wph, const float* __restrict__ bh,
    const float* __restrict__ Eh, const float* __restrict__ gh,
    const float* __restrict__ bth, const float* __restrict__ Wo,
    const float* __restrict__ bo, const float* __restrict__ Eo,
    float* __restrict__ out, int rep) {
  __shared__ float adjm[10][KJ][KJ];
  __shared__ float Hs[20][HID], Rs[20][HID], T0s[20][HID], T1s[20][HID];
  const int n = blockIdx.x, t = threadIdx.x;
  const int q = t >> 7, j = t & 127;

  const float ibb = bi[j], igg = gi[j], ibt = bti[j];

  for (int it = 0; it < rep; ++it) {
    // 0) adjacency softmax for all 10 gconvs (Ei, Eh[0..7], Eo)
    if (t < 170) {
      const int m = t / KJ, i = t % KJ;
      const float* Es = (m == 0) ? Ei : ((m <= 8) ? Eh + (size_t)(m - 1) * KJ * KJ : Eo);
      const unsigned msk = c_mask[i];
      float mx = -1e30f;
      #pragma unroll
      for (int jj = 0; jj < KJ; ++jj)
        if (msk & (1u << jj)) mx = fmaxf(mx, Es[i * KJ + jj]);
      float ev[KJ];
      float sum = 0.f;
      #pragma unroll
      for (int jj = 0; jj < KJ; ++jj) {
        const float e = (msk & (1u << jj)) ? expf(Es[i * KJ + jj] - mx) : 0.f;
        ev[jj] = e; sum += e;
      }
      const float inv = 1.f / sum;
      #pragma unroll
      for (int jj = 0; jj < KJ; ++jj) adjm[m][i][jj] = ev[jj] * inv;
    }
    // zero pad-rows 17..19
    if (t < 384) { Hs[17 + (t >> 7)][t & 127] = 0.f; Rs[17 + (t >> 7)][t & 127] = 0.f; }

    // 1) sum split-K partials of input gconv h0/h1
    {
      const float* p0 = part + (size_t)(n * KJ) * 256;
      for (int idx = t; idx < KJ * 256; idx += 512) {
        const int k = idx >> 8, jj = idx & 255;
        float v = 0.f;
        #pragma unroll
        for (int z = 0; z < SPLITK; ++z)
          v += p0[(size_t)z * NROWS * 256 + k * 256 + jj];
        if (jj < HID) T0s[k][jj] = v; else T1s[k][jj - HID] = v;
      }
    }
    __syncthreads();

    // 2) input mixing + BN + ReLU -> Hs
    mix_bn2<0>(T0s, T1s, adjm[0], ibb, igg, ibt, Hs, q, j);
    __syncthreads();

    // 3) 4 residual blocks x 2 gconvs, packed weights (float4, depth-3 ring)
    const float4* Wp4 = (const float4*)Wph;
    for (int l = 0; l < 4; ++l) {
      const int iA = 2 * l, iB = 2 * l + 1;
      {
        const float pb = bh[iA * HID + j], pg = gh[iA * HID + j], pt = bth[iA * HID + j];
        const float4* W0 = Wp4 + (size_t)(iA * 2) * 4096;       // 32*128 = 4096
        const float4* W1 = W0 + 4096;
        layer2(Hs, W0, W1, T0s, T1s, q, j);
        __syncthreads();
        mix_bn2<0>(T0s, T1s, adjm[1 + iA], pb, pg, pt, Rs, q, j);
        __syncthreads();
      }
      {
        const float pb = bh[iB * HID + j], pg = gh[iB * HID + j], pt = bth[iB * HID + j];
        const float4* W0 = Wp4 + (size_t)(iB * 2) * 4096;
        const float4* W1 = W0 + 4096;
        layer2(Rs, W0, W1, T0s, T1s, q, j);
        __syncthreads();
        mix_bn2<1>(T0s, T1s, adjm[1 + iB], pb, pg, pt, Hs, q, j);
        __syncthreads();
      }
    }

    // 4) output gconv (no BN/ReLU): 128 -> 3
    if (t < 102) {
      const int p = t / 51, rem = t % 51, i = rem / 3, e = rem % 3;
      const float* Wp = Wo + p * HID * 3 + e;
      float s = 0.f;
      #pragma unroll 4
      for (int c = 0; c < HID; ++c) s = fmaf(Hs[i][c], Wp[c * 3], s);
      if (p == 0) T0s[i][e] = s; else T1s[i][e] = s;
    }
    __syncthreads();
    if (t < 51) {
      const int i = t / 3, e = t % 3;
      const float (*A)[KJ] = adjm[9];
      float s = bo[e];
      #pragma unroll
      for (int jj = 0; jj < KJ; ++jj) s = fmaf(A[i][jj], T1s[jj][e], s);
      s += A[i][i] * (T0s[i][e] - T1s[i][e]);
      out[(n * KJ + i) * 3 + e] = s;
    }
    __syncthreads();   // protect shared reuse across rep iterations
  }
}

// ---------------------------------------------------------------------------
extern "C" void kernel_launch(void* const* d_in, const int* in_sizes, int n_in,
                              void* d_out, int out_size, void* d_ws, size_t ws_size,
                              hipStream_t stream) {
  const float* x       = (const float*)d_in[0];
  const float* heatmap = (const float*)d_in[1];
  const float* bbox    = (const float*)d_in[2];
  const float* pos_w   = (const float*)d_in[3];
  const float* pos_b   = (const float*)d_in[4];
  const float* Wi      = (const float*)d_in[5];
  const float* bi      = (const float*)d_in[6];
  const float* Ei      = (const float*)d_in[7];
  const float* gi      = (const float*)d_in[8];
  const float* bti     = (const float*)d_in[9];
  const float* Wh      = (const float*)d_in[10];
  const float* bh      = (const float*)d_in[11];
  const float* Eh      = (const float*)d_in[12];
  const float* gh      = (const float*)d_in[13];
  const float* bth     = (const float*)d_in[14];
  const float* Wo      = (const float*)d_in[15];
  const float* bo      = (const float*)d_in[16];
  const float* Eo      = (const float*)d_in[17];
  float* out = (float*)d_out;

  // ws layout (floats): h[544*2112] | part[4*544*256] | Wpi[540672] | Wph[262144] | locs
  float* h_ws = (float*)d_ws;
  float* part = h_ws + (size_t)NROWS * CEMB;
  float* Wpi  = part + (size_t)SPLITK * NROWS * 256;
  float* Wph  = Wpi + (size_t)2 * CEMB * HID;
  int*   locs = (int*)(Wph + (size_t)8 * 2 * HID * HID);

  k_pack<<<2112, 256, 0, stream>>>(Wi, Wh, Wpi, Wph);
  k_loc<<<NROWS, 256, 0, stream>>>(heatmap, bbox, pos_w, pos_b, h_ws, locs);
  k_feat<<<dim3(NROWS, 4), 256, 0, stream>>>(x, locs, h_ws, REP_FEAT);
  k_gemm_in<<<dim3(34, 4, SPLITK), 256, 0, stream>>>(h_ws, Wpi, part);
  k_gcn<<<NB, 512, 0, stream>>>(part, Ei, bi, gi, bti, Wph, bh, Eh, gh, bth,
                                Wo, bo, Eo, out, REP_GCN);
}

// Round 8
// 1243.919 us; speedup vs baseline: 5.5471x; 5.5471x over previous
//
#include <hip/hip_runtime.h>

// Problem constants (from reference)
#define NB    32
#define KJ    17
#define CIN   2048
#define HWSZ  4096     // H*W = 64*64
#define WDIM  64
#define CEMB  2112     // 64 + 2048
#define HID   128
#define NROWS (NB*KJ)  // 544
#define SPLITK 4

// Skeleton adjacency mask (H36M edges + diagonal), row i -> bitmask over j
__device__ __constant__ unsigned c_mask[KJ] = {
  0x00093u, 0x00007u, 0x0000Eu, 0x0000Cu, 0x00031u, 0x00070u, 0x00060u,
  0x00181u, 0x04B80u, 0x00700u, 0x00600u, 0x01900u, 0x03800u, 0x03000u,
  0x0C100u, 0x1C000u, 0x18000u
};

// NOTE: function, not macro — a macro param named `w` collides with the `.w`
// member under preprocessor substitution (round-7 compile failure).
__device__ __forceinline__ float fma4(const float4 s, const float4 wv, float a) {
  return fmaf(s.x, wv.x, fmaf(s.y, wv.y, fmaf(s.z, wv.z, fmaf(s.w, wv.w, a))));
}

// ---------------------------------------------------------------------------
// K_loc_pack: blocks 0..543 = heatmap argmax + posemb; blocks 544.. = weight
// repack (gather-read, coalesced float4 write).
// Wpi4[(p*528+c4)*128+d] = {Wi[p][c4*4+m][d]}m=0..3   (528 blocks)
// Wph4[(lp*32+c4)*128+d] = {Wh[lp][c4*4+m][d]}m=0..3  (256 blocks)
// ---------------------------------------------------------------------------
__global__ __launch_bounds__(256) void k_loc_pack(
    const float* __restrict__ heatmap, const float* __restrict__ bbox,
    const float* __restrict__ pos_w, const float* __restrict__ pos_b,
    const float* __restrict__ Wi, const float* __restrict__ Wh,
    float* __restrict__ h_ws, int* __restrict__ locs,
    float4* __restrict__ Wpi4, float4* __restrict__ Wph4) {
  const int blk = blockIdx.x;
  const int t = threadIdx.x;

  if (blk >= NROWS) {                    // ---- packing blocks ----
    const int pb = blk - NROWS;
    if (pb < 528) {                      // Wpi: 135168 float4
      const int idx4 = pb * 256 + t;
      const int d = idx4 & 127, rest = idx4 >> 7;
      const int c4 = rest % 528, p = rest / 528;
      const float* src = Wi + ((size_t)(p * CEMB + c4 * 4)) * HID + d;
      Wpi4[((size_t)p * 528 + c4) * 128 + d] =
          make_float4(src[0], src[HID], src[2 * HID], src[3 * HID]);
    } else {                             // Wph: 65536 float4
      const int idx4 = (pb - 528) * 256 + t;
      const int d = idx4 & 127, rest = idx4 >> 7;
      const int c4 = rest & 31, lp = rest >> 5;
      const float* src = Wh + ((size_t)(lp * HID + c4 * 4)) * HID + d;
      Wph4[((size_t)lp * 32 + c4) * 128 + d] =
          make_float4(src[0], src[HID], src[2 * HID], src[3 * HID]);
    }
    return;
  }

  // ---- loc blocks ----
  const int b = blk;                     // n*17 + k
  const int n = b / KJ;
  __shared__ float svals[256];
  __shared__ int   sidx[256];

  const float4* hm4 = (const float4*)(heatmap + (size_t)b * HWSZ);
  float best = -1e30f; int bidx = 0;
  #pragma unroll
  for (int k = 0; k < 4; ++k) {
    const int vi = k * 256 + t;
    const float4 v = hm4[vi];
    const int base = vi * 4;
    if (v.x > best) { best = v.x; bidx = base;     }
    if (v.y > best) { best = v.y; bidx = base + 1; }
    if (v.z > best) { best = v.z; bidx = base + 2; }
    if (v.w > best) { best = v.w; bidx = base + 3; }
  }
  svals[t] = best; sidx[t] = bidx;
  __syncthreads();
  for (int s = 128; s > 0; s >>= 1) {
    if (t < s) {
      const float v2 = svals[t + s]; const int i2 = sidx[t + s];
      if (v2 > svals[t] || (v2 == svals[t] && i2 < sidx[t])) {
        svals[t] = v2; sidx[t] = i2;
      }
    }
    __syncthreads();
  }
  const int loc = sidx[0];
  if (t == 0) locs[b] = loc;

  if (t < 64) {
    const float kx = (float)(loc & (WDIM - 1));
    const float ky = (float)(loc >> 6);
    float in6[6];
    in6[0] = kx * (2.0f / 64.0f) - 1.0f;
    in6[1] = ky * (2.0f / 64.0f) - 1.0f;
    in6[2] = bbox[n * 4 + 0] * (2.0f / 1920.0f) - 1.0f;
    in6[3] = bbox[n * 4 + 1] * (2.0f / 1080.0f) - 1.0f;
    in6[4] = bbox[n * 4 + 2] * (1.0f / 1920.0f);
    in6[5] = bbox[n * 4 + 3] * (1.0f / 1080.0f);
    float acc = pos_b[t];
    #pragma unroll
    for (int c = 0; c < 6; ++c) acc = fmaf(in6[c], pos_w[c * 64 + t], acc);
    h_ws[(size_t)b * CEMB + t] = acc;
  }
}

// ---------------------------------------------------------------------------
// K_feat: scattered feature gather x[n, c, loc] -> h[:,64:2112]
// ---------------------------------------------------------------------------
__global__ __launch_bounds__(256) void k_feat(
    const float* __restrict__ x, const int* __restrict__ locs,
    float* __restrict__ h_ws) {
  const int b = blockIdx.x;
  const int n = b / KJ;
  const int t = threadIdx.x;
  const int loc = locs[b];
  const int c0 = blockIdx.y * 512 + t;
  const float* xn = x + (size_t)n * CIN * HWSZ + loc;
  float* hrow = h_ws + (size_t)b * CEMB + 64;
  const float v0 = xn[(size_t)c0 * HWSZ];
  const float v1 = xn[(size_t)(c0 + 256) * HWSZ];
  hrow[c0] = v0;
  hrow[c0 + 256] = v1;
}

// ---------------------------------------------------------------------------
// K_gemm: input GEMM  C[544][256] = h[544][2112] @ [Wi0|Wi1], split-K=4
// grid (34, 4, 4), block 256. Batch-dbuf packed-W float4 loads, static idx.
// ---------------------------------------------------------------------------
__global__ __launch_bounds__(256) void k_gemm_in(
    const float* __restrict__ Wpi_f, const float* __restrict__ h_ws,
    float* __restrict__ part) {
  const int bm = blockIdx.x, bn = blockIdx.y, bz = blockIdx.z;
  const int t = threadIdx.x;
  const int lane = t & 63, g = t >> 6;          // row group (4 rows each)
  const int j = bn * 64 + lane;                 // output col 0..255
  const int p = j >> 7, d = j & 127;
  const int row0 = bm * 16;

  const float4* W4 = (const float4*)Wpi_f + ((size_t)p * 528 + bz * 132) * 128 + d;
  const int k0 = bz * 528;

  __shared__ float At[16][48];                  // 12 c4-chunks per stage
  float acc[4] = {0.f, 0.f, 0.f, 0.f};
  float4 wbuf[2][12];

  #pragma unroll
  for (int u = 0; u < 12; ++u) wbuf[0][u] = W4[(size_t)u * 128];

  #pragma unroll
  for (int st = 0; st < 11; ++st) {             // compile-time -> static wbuf idx
    const int kk = k0 + st * 48;
    __syncthreads();
    for (int idx = t; idx < 16 * 48; idx += 256) {
      const int r = idx / 48, c = idx - r * 48;
      At[r][c] = h_ws[(size_t)(row0 + r) * CEMB + kk + c];
    }
    __syncthreads();
    if (st < 10) {
      #pragma unroll
      for (int u = 0; u < 12; ++u)
        wbuf[(st + 1) & 1][u] = W4[(size_t)((st + 1) * 12 + u) * 128];
    }
    #pragma unroll
    for (int u = 0; u < 12; ++u) {
      #pragma unroll
      for (int r = 0; r < 4; ++r) {
        const float4 s = *(const float4*)&At[g * 4 + r][u * 4];
        acc[r] = fma4(s, wbuf[st & 1][u], acc[r]);
      }
    }
  }
  #pragma unroll
  for (int r = 0; r < 4; ++r) {
    part[((size_t)bz * NROWS + row0 + g * 4 + r) * 256 + j] = acc[r];
  }
}

// ---------------------------------------------------------------------------
// K_gcn: grid 32 (one block/sample), block 512: q = t>>7 (5 rows), j = t&127.
// layer3: batch-dbuf weight loads (8 chunks/batch), fully static indexing.
// ---------------------------------------------------------------------------
__device__ __forceinline__ void layer3(
    const float (*S)[HID], const float4* __restrict__ W0,
    const float4* __restrict__ W1, float (*O0)[HID], float (*O1)[HID],
    int q, int j) {
  const int r0 = q * 5;                 // rows r0..r0+4 (rows 17..19 are pad)
  float a0[5] = {0.f, 0.f, 0.f, 0.f, 0.f};
  float a1[5] = {0.f, 0.f, 0.f, 0.f, 0.f};
  float4 w0[2][8], w1[2][8];

  #pragma unroll
  for (int u = 0; u < 8; ++u) {
    w0[0][u] = W0[u * 128 + j];
    w1[0][u] = W1[u * 128 + j];
  }
  #pragma unroll
  for (int b = 0; b < 4; ++b) {         // compile-time -> static buffer idx
    const int cur = b & 1, nxt = cur ^ 1;
    if (b < 3) {
      #pragma unroll
      for (int u = 0; u < 8; ++u) {
        w0[nxt][u] = W0[((b + 1) * 8 + u) * 128 + j];
        w1[nxt][u] = W1[((b + 1) * 8 + u) * 128 + j];
      }
    }
    #pragma unroll
    for (int u = 0; u < 8; ++u) {
      const int cc = b * 8 + u;
      #pragma unroll
      for (int r = 0; r < 5; ++r) {
        const float4 s = *(const float4*)&S[r0 + r][cc * 4];  // wave-uniform bcast
        a0[r] = fma4(s, w0[cur][u], a0[r]);
        a1[r] = fma4(s, w1[cur][u], a1[r]);
      }
    }
  }
  #pragma unroll
  for (int r = 0; r < 5; ++r) { O0[r0 + r][j] = a0[r]; O1[r0 + r][j] = a1[r]; }
}

template <int ADD>
__device__ __forceinline__ void mix_bn2(
    const float (*T0)[HID], const float (*T1)[HID], const float (*A)[KJ],
    float pb, float pg, float pt, float (*dst)[HID], int q, int d) {
  const float gsv = pg * 0.99999500003749969f;  // gamma * rsqrt(1+1e-5)
  for (int i = q; i < KJ; i += 4) {
    float s = 0.f;
    #pragma unroll
    for (int jj = 0; jj < KJ; ++jj) s = fmaf(A[i][jj], T1[jj][d], s);
    s += A[i][i] * (T0[i][d] - T1[i][d]);   // diag term h1 -> h0
    const float v = fmaxf(fmaf(s + pb, gsv, pt), 0.f);
    if (ADD) dst[i][d] += v; else dst[i][d] = v;
  }
}

__global__ __launch_bounds__(512) void k_gcn(
    const float* __restrict__ part,
    const float* __restrict__ Ei, const float* __restrict__ bi,
    const float* __restrict__ gi, const float* __restrict__ bti,
    const float* __restrict__ Wph, const float* __restrict__ bh,
    const float* __restrict__ Eh, const float* __restrict__ gh,
    const float* __restrict__ bth, const float* __restrict__ Wo,
    const float* __restrict__ bo, const float* __restrict__ Eo,
    float* __restrict__ out) {
  __shared__ float adjm[10][KJ][KJ];
  __shared__ float Hs[20][HID], Rs[20][HID], T0s[20][HID], T1s[20][HID];
  const int n = blockIdx.x, t = threadIdx.x;
  const int q = t >> 7, j = t & 127;

  // hoist ALL BN params to registers (overlaps with softmax + partial load)
  const float ibb = bi[j], igg = gi[j], ibt = bti[j];
  float pbh[8], pgh[8], pth[8];
  #pragma unroll
  for (int i = 0; i < 8; ++i) {
    pbh[i] = bh[i * HID + j]; pgh[i] = gh[i * HID + j]; pth[i] = bth[i * HID + j];
  }

  // 0) adjacency softmax for all 10 gconvs (Ei, Eh[0..7], Eo)
  if (t < 170) {
    const int m = t / KJ, i = t % KJ;
    const float* Es = (m == 0) ? Ei : ((m <= 8) ? Eh + (size_t)(m - 1) * KJ * KJ : Eo);
    const unsigned msk = c_mask[i];
    float mx = -1e30f;
    #pragma unroll
    for (int jj = 0; jj < KJ; ++jj)
      if (msk & (1u << jj)) mx = fmaxf(mx, Es[i * KJ + jj]);
    float ev[KJ];
    float sum = 0.f;
    #pragma unroll
    for (int jj = 0; jj < KJ; ++jj) {
      const float e = (msk & (1u << jj)) ? expf(Es[i * KJ + jj] - mx) : 0.f;
      ev[jj] = e; sum += e;
    }
    const float inv = 1.f / sum;
    #pragma unroll
    for (int jj = 0; jj < KJ; ++jj) adjm[m][i][jj] = ev[jj] * inv;
  }
  // zero pad-rows 17..19
  if (t < 384) { Hs[17 + (t >> 7)][t & 127] = 0.f; Rs[17 + (t >> 7)][t & 127] = 0.f; }

  // 1) sum split-K partials of input gconv h0/h1
  {
    const float* p0 = part + (size_t)(n * KJ) * 256;
    for (int idx = t; idx < KJ * 256; idx += 512) {
      const int k = idx >> 8, jj = idx & 255;
      float v = 0.f;
      #pragma unroll
      for (int z = 0; z < SPLITK; ++z)
        v += p0[(size_t)z * NROWS * 256 + k * 256 + jj];
      if (jj < HID) T0s[k][jj] = v; else T1s[k][jj - HID] = v;
    }
  }
  __syncthreads();

  // 2) input mixing + BN + ReLU -> Hs
  mix_bn2<0>(T0s, T1s, adjm[0], ibb, igg, ibt, Hs, q, j);
  __syncthreads();

  // 3) 4 residual blocks x 2 gconvs, packed weights (batch-dbuf float4)
  const float4* Wp4 = (const float4*)Wph;
  #pragma unroll
  for (int l = 0; l < 4; ++l) {
    const int iA = 2 * l, iB = 2 * l + 1;
    layer3(Hs, Wp4 + (size_t)(iA * 2) * 4096, Wp4 + (size_t)(iA * 2 + 1) * 4096,
           T0s, T1s, q, j);
    __syncthreads();
    mix_bn2<0>(T0s, T1s, adjm[1 + iA], pbh[iA], pgh[iA], pth[iA], Rs, q, j);
    __syncthreads();
    layer3(Rs, Wp4 + (size_t)(iB * 2) * 4096, Wp4 + (size_t)(iB * 2 + 1) * 4096,
           T0s, T1s, q, j);
    __syncthreads();
    mix_bn2<1>(T0s, T1s, adjm[1 + iB], pbh[iB], pgh[iB], pth[iB], Hs, q, j);
    __syncthreads();
  }

  // 4) output gconv (no BN/ReLU): 128 -> 3
  if (t < 102) {
    const int p = t / 51, rem = t % 51, i = rem / 3, e = rem % 3;
    const float* Wp = Wo + p * HID * 3 + e;
    float s = 0.f;
    #pragma unroll 4
    for (int c = 0; c < HID; ++c) s = fmaf(Hs[i][c], Wp[c * 3], s);
    if (p == 0) T0s[i][e] = s; else T1s[i][e] = s;
  }
  __syncthreads();
  if (t < 51) {
    const int i = t / 3, e = t % 3;
    const float (*A)[KJ] = adjm[9];
    float s = bo[e];
    #pragma unroll
    for (int jj = 0; jj < KJ; ++jj) s = fmaf(A[i][jj], T1s[jj][e], s);
    s += A[i][i] * (T0s[i][e] - T1s[i][e]);
    out[(n * KJ + i) * 3 + e] = s;
  }
}

// ---------------------------------------------------------------------------
extern "C" void kernel_launch(void* const* d_in, const int* in_sizes, int n_in,
                              void* d_out, int out_size, void* d_ws, size_t ws_size,
                              hipStream_t stream) {
  const float* x       = (const float*)d_in[0];
  const float* heatmap = (const float*)d_in[1];
  const float* bbox    = (const float*)d_in[2];
  const float* pos_w   = (const float*)d_in[3];
  const float* pos_b   = (const float*)d_in[4];
  const float* Wi      = (const float*)d_in[5];
  const float* bi      = (const float*)d_in[6];
  const float* Ei      = (const float*)d_in[7];
  const float* gi      = (const float*)d_in[8];
  const float* bti     = (const float*)d_in[9];
  const float* Wh      = (const float*)d_in[10];
  const float* bh      = (const float*)d_in[11];
  const float* Eh      = (const float*)d_in[12];
  const float* gh      = (const float*)d_in[13];
  const float* bth     = (const float*)d_in[14];
  const float* Wo      = (const float*)d_in[15];
  const float* bo      = (const float*)d_in[16];
  const float* Eo      = (const float*)d_in[17];
  float* out = (float*)d_out;

  // ws layout (floats): h[544*2112] | part[4*544*256] | Wpi[540672] | Wph[262144] | locs
  float* h_ws = (float*)d_ws;
  float* part = h_ws + (size_t)NROWS * CEMB;
  float* Wpi  = part + (size_t)SPLITK * NROWS * 256;
  float* Wph  = Wpi + (size_t)2 * CEMB * HID;
  int*   locs = (int*)(Wph + (size_t)8 * 2 * HID * HID);

  k_loc_pack<<<NROWS + 528 + 256, 256, 0, stream>>>(
      heatmap, bbox, pos_w, pos_b, Wi, Wh, h_ws, locs,
      (float4*)Wpi, (float4*)Wph);
  k_feat<<<dim3(NROWS, 4), 256, 0, stream>>>(x, locs, h_ws);
  k_gemm_in<<<dim3(34, 4, SPLITK), 256, 0, stream>>>(Wpi, h_ws, part);
  k_gcn<<<NB, 512, 0, stream>>>(part, Ei, bi, gi, bti, Wph, bh, Eh, gh, bth,
                                Wo, bo, Eo, out);
}

// Round 9
// 132.313 us; speedup vs baseline: 52.1501x; 9.4013x over previous
//
#include <hip/hip_runtime.h>

// Problem constants (from reference)
#define NB    32
#define KJ    17
#define CIN   2048
#define HWSZ  4096     // H*W = 64*64
#define WDIM  64
#define CEMB  2112     // 64 + 2048
#define HID   128
#define NROWS (NB*KJ)  // 544
#define SPLITK 4

// Skeleton adjacency mask (H36M edges + diagonal), row i -> bitmask over j
__device__ __constant__ unsigned c_mask[KJ] = {
  0x00093u, 0x00007u, 0x0000Eu, 0x0000Cu, 0x00031u, 0x00070u, 0x00060u,
  0x00181u, 0x04B80u, 0x00700u, 0x00600u, 0x01900u, 0x03800u, 0x03000u,
  0x0C100u, 0x1C000u, 0x18000u
};

// function, not macro: macro param named `w` collides with `.w` member
__device__ __forceinline__ float fma4(const float4 s, const float4 wv, float a) {
  return fmaf(s.x, wv.x, fmaf(s.y, wv.y, fmaf(s.z, wv.z, fmaf(s.w, wv.w, a))));
}

// ---------------------------------------------------------------------------
// K_front: blocks 0..543: heatmap argmax + posemb + OWN-ROW feature gather.
//          blocks 544..1327: weight repack (gather-read, coalesced write).
// ---------------------------------------------------------------------------
__global__ __launch_bounds__(256) void k_front(
    const float* __restrict__ heatmap, const float* __restrict__ bbox,
    const float* __restrict__ pos_w, const float* __restrict__ pos_b,
    const float* __restrict__ Wi, const float* __restrict__ Wh,
    const float* __restrict__ x, float* __restrict__ h_ws,
    float4* __restrict__ Wpi4, float4* __restrict__ Wph4) {
  const int blk = blockIdx.x;
  const int t = threadIdx.x;

  if (blk >= NROWS) {                    // ---- packing blocks ----
    const int pb = blk - NROWS;
    if (pb < 528) {                      // Wpi: 135168 float4
      const int idx4 = pb * 256 + t;
      const int d = idx4 & 127, rest = idx4 >> 7;
      const int c4 = rest % 528, p = rest / 528;
      const float* src = Wi + ((size_t)(p * CEMB + c4 * 4)) * HID + d;
      Wpi4[((size_t)p * 528 + c4) * 128 + d] =
          make_float4(src[0], src[HID], src[2 * HID], src[3 * HID]);
    } else {                             // Wph: 65536 float4
      const int idx4 = (pb - 528) * 256 + t;
      const int d = idx4 & 127, rest = idx4 >> 7;
      const int c4 = rest & 31, lp = rest >> 5;
      const float* src = Wh + ((size_t)(lp * HID + c4 * 4)) * HID + d;
      Wph4[((size_t)lp * 32 + c4) * 128 + d] =
          make_float4(src[0], src[HID], src[2 * HID], src[3 * HID]);
    }
    return;
  }

  // ---- per-(n,k) blocks ----
  const int b = blk;                     // n*17 + k
  const int n = b / KJ;
  __shared__ float svals[256];
  __shared__ int   sidx[256];

  const float4* hm4 = (const float4*)(heatmap + (size_t)b * HWSZ);
  float best = -1e30f; int bidx = 0;
  #pragma unroll
  for (int k = 0; k < 4; ++k) {
    const int vi = k * 256 + t;
    const float4 v = hm4[vi];
    const int base = vi * 4;
    if (v.x > best) { best = v.x; bidx = base;     }
    if (v.y > best) { best = v.y; bidx = base + 1; }
    if (v.z > best) { best = v.z; bidx = base + 2; }
    if (v.w > best) { best = v.w; bidx = base + 3; }
  }
  svals[t] = best; sidx[t] = bidx;
  __syncthreads();
  for (int s = 128; s > 0; s >>= 1) {
    if (t < s) {
      const float v2 = svals[t + s]; const int i2 = sidx[t + s];
      if (v2 > svals[t] || (v2 == svals[t] && i2 < sidx[t])) {
        svals[t] = v2; sidx[t] = i2;
      }
    }
    __syncthreads();
  }
  const int loc = sidx[0];               // valid in all threads

  if (t < 64) {
    const float kx = (float)(loc & (WDIM - 1));
    const float ky = (float)(loc >> 6);
    float in6[6];
    in6[0] = kx * (2.0f / 64.0f) - 1.0f;
    in6[1] = ky * (2.0f / 64.0f) - 1.0f;
    in6[2] = bbox[n * 4 + 0] * (2.0f / 1920.0f) - 1.0f;
    in6[3] = bbox[n * 4 + 1] * (2.0f / 1080.0f) - 1.0f;
    in6[4] = bbox[n * 4 + 2] * (1.0f / 1920.0f);
    in6[5] = bbox[n * 4 + 3] * (1.0f / 1080.0f);
    float acc = pos_b[t];
    #pragma unroll
    for (int c = 0; c < 6; ++c) acc = fmaf(in6[c], pos_w[c * 64 + t], acc);
    h_ws[(size_t)b * CEMB + t] = acc;
  }

  // own-row scattered gather: 8 channels/thread, independent loads
  const float* xn = x + (size_t)n * CIN * HWSZ + loc;
  float* hrow = h_ws + (size_t)b * CEMB + 64;
  #pragma unroll
  for (int k = 0; k < 8; ++k) {
    const int c = k * 256 + t;
    hrow[c] = xn[(size_t)c * HWSZ];
  }
}

// ---------------------------------------------------------------------------
// K_gemm: input GEMM  C[544][256] = h[544][2112] @ [Wi0|Wi1], split-K=4
// grid (34, 4, 4), block 256. Static 3-slot weight ring (12 VGPR, no movs).
// ---------------------------------------------------------------------------
__global__ __launch_bounds__(256) void k_gemm_in(
    const float* __restrict__ Wpi_f, const float* __restrict__ h_ws,
    float* __restrict__ part) {
  const int bm = blockIdx.x, bn = blockIdx.y, bz = blockIdx.z;
  const int t = threadIdx.x;
  const int lane = t & 63, g = t >> 6;          // row group (4 rows each)
  const int j = bn * 64 + lane;                 // output col 0..255
  const int p = j >> 7, d = j & 127;
  const int row0 = bm * 16;

  const float4* W4 = (const float4*)Wpi_f + ((size_t)p * 528 + bz * 132) * 128 + d;
  const int k0 = bz * 528;

  __shared__ float At[16][48];                  // 12 c4-chunks per stage
  float acc[4] = {0.f, 0.f, 0.f, 0.f};
  float4 ws[3];                                 // 3-slot ring, slot = ci % 3

  ws[0] = W4[0];
  ws[1] = W4[128];

  for (int st = 0; st < 11; ++st) {
    const int kk = k0 + st * 48;
    __syncthreads();
    for (int idx = t; idx < 16 * 48; idx += 256) {
      const int r = idx / 48, c = idx - r * 48;
      At[r][c] = h_ws[(size_t)(row0 + r) * CEMB + kk + c];
    }
    __syncthreads();
    #pragma unroll
    for (int u = 0; u < 12; ++u) {              // slot (u%3) static after unroll
      {
        int pf = st * 12 + u + 2;               // prefetch chunk, clamp at end
        pf = pf < 132 ? pf : 131;
        ws[(u + 2) % 3] = W4[(size_t)pf * 128];
      }
      const float4 wv = ws[u % 3];
      #pragma unroll
      for (int r = 0; r < 4; ++r) {
        const float4 s = *(const float4*)&At[g * 4 + r][u * 4];
        acc[r] = fma4(s, wv, acc[r]);
      }
    }
  }
  #pragma unroll
  for (int r = 0; r < 4; ++r) {
    part[((size_t)bz * NROWS + row0 + g * 4 + r) * 256 + j] = acc[r];
  }
}

// ---------------------------------------------------------------------------
// K_gcn: grid 32 (one block/sample), block 512: q = t>>7 (5 rows), j = t&127.
// layer4s: static 4-slot weight ring per path (32 VGPR total, no movs).
// ---------------------------------------------------------------------------
__device__ __forceinline__ void layer4s(
    const float (*S)[HID], const float4* __restrict__ W0,
    const float4* __restrict__ W1, float (*O0)[HID], float (*O1)[HID],
    int q, int j) {
  const int r0 = q * 5;                 // rows r0..r0+4 (rows 17..19 are pad)
  float a0[5] = {0.f, 0.f, 0.f, 0.f, 0.f};
  float a1[5] = {0.f, 0.f, 0.f, 0.f, 0.f};
  float4 w0s[4], w1s[4];                // slot = cc % 4, static after unroll

  #pragma unroll
  for (int u = 0; u < 3; ++u) {
    w0s[u] = W0[u * 128 + j];
    w1s[u] = W1[u * 128 + j];
  }
  #pragma unroll
  for (int cc = 0; cc < 32; ++cc) {
    if (cc < 29) {                      // prefetch chunk cc+3 (static guard)
      w0s[(cc + 3) % 4] = W0[(cc + 3) * 128 + j];
      w1s[(cc + 3) % 4] = W1[(cc + 3) * 128 + j];
    }
    const float4 wv0 = w0s[cc % 4];
    const float4 wv1 = w1s[cc % 4];
    #pragma unroll
    for (int r = 0; r < 5; ++r) {
      const float4 s = *(const float4*)&S[r0 + r][cc * 4];  // wave-uniform bcast
      a0[r] = fma4(s, wv0, a0[r]);
      a1[r] = fma4(s, wv1, a1[r]);
    }
  }
  #pragma unroll
  for (int r = 0; r < 5; ++r) { O0[r0 + r][j] = a0[r]; O1[r0 + r][j] = a1[r]; }
}

template <int ADD>
__device__ __forceinline__ void mix_bn2(
    const float (*T0)[HID], const float (*T1)[HID], const float (*A)[KJ],
    float pb, float pg, float pt, float (*dst)[HID], int q, int d) {
  const float gsv = pg * 0.99999500003749969f;  // gamma * rsqrt(1+1e-5)
  for (int i = q; i < KJ; i += 4) {
    float s = 0.f;
    #pragma unroll
    for (int jj = 0; jj < KJ; ++jj) s = fmaf(A[i][jj], T1[jj][d], s);
    s += A[i][i] * (T0[i][d] - T1[i][d]);   // diag term h1 -> h0
    const float v = fmaxf(fmaf(s + pb, gsv, pt), 0.f);
    if (ADD) dst[i][d] += v; else dst[i][d] = v;
  }
}

__global__ __launch_bounds__(512) void k_gcn(
    const float* __restrict__ part,
    const float* __restrict__ Ei, const float* __restrict__ bi,
    const float* __restrict__ gi, const float* __restrict__ bti,
    const float* __restrict__ Wph, const float* __restrict__ bh,
    const float* __restrict__ Eh, const float* __restrict__ gh,
    const float* __restrict__ bth, const float* __restrict__ Wo,
    const float* __restrict__ bo, const float* __restrict__ Eo,
    float* __restrict__ out) {
  __shared__ float adjm[10][KJ][KJ];
  __shared__ float Hs[20][HID], Rs[20][HID], T0s[20][HID], T1s[20][HID];
  const int n = blockIdx.x, t = threadIdx.x;
  const int q = t >> 7, j = t & 127;

  const float ibb = bi[j], igg = gi[j], ibt = bti[j];

  // 0) adjacency softmax for all 10 gconvs (Ei, Eh[0..7], Eo)
  if (t < 170) {
    const int m = t / KJ, i = t % KJ;
    const float* Es = (m == 0) ? Ei : ((m <= 8) ? Eh + (size_t)(m - 1) * KJ * KJ : Eo);
    const unsigned msk = c_mask[i];
    float mx = -1e30f;
    #pragma unroll
    for (int jj = 0; jj < KJ; ++jj)
      if (msk & (1u << jj)) mx = fmaxf(mx, Es[i * KJ + jj]);
    float ev[KJ];
    float sum = 0.f;
    #pragma unroll
    for (int jj = 0; jj < KJ; ++jj) {
      const float e = (msk & (1u << jj)) ? expf(Es[i * KJ + jj] - mx) : 0.f;
      ev[jj] = e; sum += e;
    }
    const float inv = 1.f / sum;
    #pragma unroll
    for (int jj = 0; jj < KJ; ++jj) adjm[m][i][jj] = ev[jj] * inv;
  }
  // zero pad-rows 17..19
  if (t < 384) { Hs[17 + (t >> 7)][t & 127] = 0.f; Rs[17 + (t >> 7)][t & 127] = 0.f; }

  // 1) sum split-K partials of input gconv h0/h1
  {
    const float* p0 = part + (size_t)(n * KJ) * 256;
    for (int idx = t; idx < KJ * 256; idx += 512) {
      const int k = idx >> 8, jj = idx & 255;
      float v = 0.f;
      #pragma unroll
      for (int z = 0; z < SPLITK; ++z)
        v += p0[(size_t)z * NROWS * 256 + k * 256 + jj];
      if (jj < HID) T0s[k][jj] = v; else T1s[k][jj - HID] = v;
    }
  }
  __syncthreads();

  // 2) input mixing + BN + ReLU -> Hs
  mix_bn2<0>(T0s, T1s, adjm[0], ibb, igg, ibt, Hs, q, j);
  __syncthreads();

  // 3) 4 residual blocks x 2 gconvs, packed weights (static 4-slot ring)
  const float4* Wp4 = (const float4*)Wph;
  for (int l = 0; l < 4; ++l) {
    const int iA = 2 * l, iB = 2 * l + 1;
    {
      const float pb = bh[iA * HID + j], pg = gh[iA * HID + j], pt = bth[iA * HID + j];
      layer4s(Hs, Wp4 + (size_t)(iA * 2) * 4096, Wp4 + (size_t)(iA * 2 + 1) * 4096,
              T0s, T1s, q, j);
      __syncthreads();
      mix_bn2<0>(T0s, T1s, adjm[1 + iA], pb, pg, pt, Rs, q, j);
      __syncthreads();
    }
    {
      const float pb = bh[iB * HID + j], pg = gh[iB * HID + j], pt = bth[iB * HID + j];
      layer4s(Rs, Wp4 + (size_t)(iB * 2) * 4096, Wp4 + (size_t)(iB * 2 + 1) * 4096,
              T0s, T1s, q, j);
      __syncthreads();
      mix_bn2<1>(T0s, T1s, adjm[1 + iB], pb, pg, pt, Hs, q, j);
      __syncthreads();
    }
  }

  // 4) output gconv (no BN/ReLU): 128 -> 3
  if (t < 102) {
    const int p = t / 51, rem = t % 51, i = rem / 3, e = rem % 3;
    const float* Wp = Wo + p * HID * 3 + e;
    float s = 0.f;
    #pragma unroll 4
    for (int c = 0; c < HID; ++c) s = fmaf(Hs[i][c], Wp[c * 3], s);
    if (p == 0) T0s[i][e] = s; else T1s[i][e] = s;
  }
  __syncthreads();
  if (t < 51) {
    const int i = t / 3, e = t % 3;
    const float (*A)[KJ] = adjm[9];
    float s = bo[e];
    #pragma unroll
    for (int jj = 0; jj < KJ; ++jj) s = fmaf(A[i][jj], T1s[jj][e], s);
    s += A[i][i] * (T0s[i][e] - T1s[i][e]);
    out[(n * KJ + i) * 3 + e] = s;
  }
}

// ---------------------------------------------------------------------------
extern "C" void kernel_launch(void* const* d_in, const int* in_sizes, int n_in,
                              void* d_out, int out_size, void* d_ws, size_t ws_size,
                              hipStream_t stream) {
  const float* x       = (const float*)d_in[0];
  const float* heatmap = (const float*)d_in[1];
  const float* bbox    = (const float*)d_in[2];
  const float* pos_w   = (const float*)d_in[3];
  const float* pos_b   = (const float*)d_in[4];
  const float* Wi      = (const float*)d_in[5];
  const float* bi      = (const float*)d_in[6];
  const float* Ei      = (const float*)d_in[7];
  const float* gi      = (const float*)d_in[8];
  const float* bti     = (const float*)d_in[9];
  const float* Wh      = (const float*)d_in[10];
  const float* bh      = (const float*)d_in[11];
  const float* Eh      = (const float*)d_in[12];
  const float* gh      = (const float*)d_in[13];
  const float* bth     = (const float*)d_in[14];
  const float* Wo      = (const float*)d_in[15];
  const float* bo      = (const float*)d_in[16];
  const float* Eo      = (const float*)d_in[17];
  float* out = (float*)d_out;

  // ws layout (floats): h[544*2112] | part[4*544*256] | Wpi[540672] | Wph[262144]
  float* h_ws = (float*)d_ws;
  float* part = h_ws + (size_t)NROWS * CEMB;
  float* Wpi  = part + (size_t)SPLITK * NROWS * 256;
  float* Wph  = Wpi + (size_t)2 * CEMB * HID;

  k_front<<<NROWS + 528 + 256, 256, 0, stream>>>(
      heatmap, bbox, pos_w, pos_b, Wi, Wh, x, h_ws,
      (float4*)Wpi, (float4*)Wph);
  k_gemm_in<<<dim3(34, 4, SPLITK), 256, 0, stream>>>(Wpi, h_ws, part);
  k_gcn<<<NB, 512, 0, stream>>>(part, Ei, bi, gi, bti, Wph, bh, Eh, gh, bth,
                                Wo, bo, Eo, out);
}